// Round 2
// baseline (245.247 us; speedup 1.0000x reference)
//
#include <hip/hip_runtime.h>
#include <stdint.h>
#include <math.h>

typedef __bf16 bf16;
typedef __bf16 bf16x4 __attribute__((ext_vector_type(4)));
typedef __bf16 bf16x8 __attribute__((ext_vector_type(8)));
typedef float floatx4 __attribute__((ext_vector_type(4)));
typedef float floatx16 __attribute__((ext_vector_type(16)));

#define CEXP 0.1803368801111204f  /* (1/8) * log2(e) */

// ---------------------------------------------------------------------------
// Weight pre-convert: fp32 [1024][1024] -> bf16, 4 matrices (Wq,Wk,Wv,Wo)
// ---------------------------------------------------------------------------
__global__ __launch_bounds__(256) void wcvt_kernel(
    const float* __restrict__ Wq, const float* __restrict__ Wk,
    const float* __restrict__ Wv, const float* __restrict__ Wo,
    bf16* __restrict__ dst)
{
  const float* src = (blockIdx.y == 0) ? Wq : (blockIdx.y == 1) ? Wk
                   : (blockIdx.y == 2) ? Wv : Wo;
  bf16* d = dst + (size_t)blockIdx.y * 1048576;
  const int i = (blockIdx.x * 256 + threadIdx.x) * 4;
  const floatx4 v = *(const floatx4*)(src + i);
  bf16x4 o;
#pragma unroll
  for (int j = 0; j < 4; ++j) o[j] = (bf16)v[j];
  *(bf16x4*)(d + i) = o;
}

// ---------------------------------------------------------------------------
// GEMM: C[4096,1024] = A @ Wb(bf16)^T + bias(fp32)
// 128x128 tile, BK=64, 4 waves, register-prefetch pipeline, LDS stride 72.
// mode 0: A fp32 direct; C bf16 [b,h,s,dk]
// mode 2: A fp32 direct; C bf16 [b,h,dk,s] (transposed V), LDS-coalesced store
// mode 1: A bf16 gathered from Sb [b,h,s,dk]; C fp32 [token][col]
// ---------------------------------------------------------------------------
__device__ __forceinline__ void gemm_body(
    const float* __restrict__ A, const bf16* __restrict__ Ab,
    const bf16* __restrict__ Wb, const float* __restrict__ bias,
    void* __restrict__ Cout, const int mode, const float oscale)
{
  __shared__ __align__(16) bf16 As[128 * 72];
  __shared__ __align__(16) bf16 Bs[128 * 72];
  const int tid  = threadIdx.x;
  const int wave = tid >> 6;
  const int lane = tid & 63;
  const int mlane = lane & 15;
  const int quad  = lane >> 4;
  const int m0 = blockIdx.x * 128;   // m-major grid
  const int n0 = blockIdx.y * 128;
  const int wm = (wave >> 1) * 64;
  const int wn = (wave & 1) * 64;
  const int arow = tid >> 4, ac4 = (tid & 15) * 4;  // fp32 A: 16 rows/pass
  const int wrow = tid >> 3, wc8 = (tid & 7) * 8;   // bf16: 32 rows/pass

  floatx4 a_pf[8];
  bf16x8  ab_pf[4];
  bf16x8  w_pf[4];

  auto load_a = [&](int k0) {
    if (mode == 1) {
#pragma unroll
      for (int c = 0; c < 4; ++c) {
        const int token = m0 + c * 32 + wrow;
        const int b = token >> 11, s = token & 2047;
        const int h = k0 >> 6;  // BK=64 stays within one head
        ab_pf[c] = *(const bf16x8*)(Ab + (((size_t)(b * 16 + h) * 2048 + s) << 6) + wc8);
      }
    } else {
#pragma unroll
      for (int rr = 0; rr < 8; ++rr)
        a_pf[rr] = *(const floatx4*)(A + (size_t)(m0 + rr * 16 + arow) * 1024 + k0 + ac4);
    }
  };
  auto load_w = [&](int k0) {
#pragma unroll
    for (int c = 0; c < 4; ++c)
      w_pf[c] = *(const bf16x8*)(Wb + (size_t)(n0 + c * 32 + wrow) * 1024 + k0 + wc8);
  };

  load_a(0);
  load_w(0);

  floatx4 acc[4][4] = {};

  for (int k0 = 0; k0 < 1024; k0 += 64) {
    if (mode == 1) {
#pragma unroll
      for (int c = 0; c < 4; ++c)
        *(bf16x8*)&As[(c * 32 + wrow) * 72 + wc8] = ab_pf[c];
    } else {
#pragma unroll
      for (int rr = 0; rr < 8; ++rr) {
        bf16x4 ac;
#pragma unroll
        for (int j = 0; j < 4; ++j) ac[j] = (bf16)a_pf[rr][j];
        *(bf16x4*)&As[(rr * 16 + arow) * 72 + ac4] = ac;
      }
    }
#pragma unroll
    for (int c = 0; c < 4; ++c)
      *(bf16x8*)&Bs[(c * 32 + wrow) * 72 + wc8] = w_pf[c];
    __syncthreads();

    if (k0 + 64 < 1024) { load_a(k0 + 64); load_w(k0 + 64); }

#pragma unroll
    for (int kk = 0; kk < 64; kk += 32) {
      bf16x8 af[4], bfr[4];
#pragma unroll
      for (int t = 0; t < 4; ++t) {
        af[t]  = *(const bf16x8*)&As[(wm + t * 16 + mlane) * 72 + kk + quad * 8];
        bfr[t] = *(const bf16x8*)&Bs[(wn + t * 16 + mlane) * 72 + kk + quad * 8];
      }
#pragma unroll
      for (int mt = 0; mt < 4; ++mt)
#pragma unroll
        for (int nt = 0; nt < 4; ++nt)
          acc[mt][nt] = __builtin_amdgcn_mfma_f32_16x16x32_bf16(
              af[mt], bfr[nt], acc[mt][nt], 0, 0, 0);
    }
    __syncthreads();
  }

  // epilogue
  if (mode == 2) {
    // Transpose the wave's 64x64 tile through LDS, then 16B-coalesced stores.
    bf16* T = (wave < 2) ? &As[wave * 4608] : &Bs[(wave - 2) * 4608];
#pragma unroll
    for (int nt = 0; nt < 4; ++nt) {
      const float bv = bias[n0 + wn + nt * 16 + mlane];
#pragma unroll
      for (int mt = 0; mt < 4; ++mt) {
        bf16x4 t4;
#pragma unroll
        for (int r = 0; r < 4; ++r)
          t4[r] = (bf16)((acc[mt][nt][r] + bv) * oscale);
        *(bf16x4*)&T[(nt * 16 + mlane) * 72 + mt * 16 + quad * 4] = t4;
      }
    }
    asm volatile("s_waitcnt lgkmcnt(0)" ::: "memory");  // wave-local transpose
    const int token0 = m0 + wm;            // 64-aligned -> single b
    const int bb = token0 >> 11;
    const int srow0 = token0 & 2047;
    const int h = (n0 + wn) >> 6;          // 64-aligned -> single h
    const int dl = lane >> 3;
    const int s8 = (lane & 7) * 8;
    bf16* outp = (bf16*)Cout + ((size_t)(bb * 16 + h) << 17);
#pragma unroll
    for (int p = 0; p < 8; ++p) {
      const int dk = p * 8 + dl;
      const bf16x8 v8 = *(const bf16x8*)&T[dk * 72 + s8];
      *(bf16x8*)&outp[((size_t)dk << 11) + srow0 + s8] = v8;
    }
    return;
  }

#pragma unroll
  for (int nt = 0; nt < 4; ++nt) {
    const int col = n0 + wn + nt * 16 + mlane;
    const float bv = bias[col];
#pragma unroll
    for (int mt = 0; mt < 4; ++mt) {
#pragma unroll
      for (int r = 0; r < 4; ++r) {
        const int row = m0 + wm + mt * 16 + quad * 4 + r;
        const float v = (acc[mt][nt][r] + bv) * oscale;
        if (mode == 0) {
          const int b = row >> 11, s = row & 2047;
          const int h = col >> 6, dk = col & 63;
          ((bf16*)Cout)[(((size_t)(b * 16 + h) * 2048 + s) << 6) + dk] = (bf16)v;
        } else {
          ((float*)Cout)[(size_t)row * 1024 + col] = v;
        }
      }
    }
  }
}

__global__ __launch_bounds__(256) void qkv_kernel(
    const float* __restrict__ q, const float* __restrict__ k, const float* __restrict__ v,
    const bf16* __restrict__ Wb,
    const float* __restrict__ bq, const float* __restrict__ bk, const float* __restrict__ bv,
    bf16* __restrict__ Qw, bf16* __restrict__ Kw, bf16* __restrict__ Vw)
{
  const int z = blockIdx.z;
  const float* A = (z == 0) ? q : (z == 1) ? k : v;
  const bf16* W  = Wb + (size_t)z * 1048576;
  const float* B = (z == 0) ? bq : (z == 1) ? bk : bv;
  if (z == 2)      gemm_body(A, nullptr, W, B, Vw, 2, 1.0f);
  else if (z == 1) gemm_body(A, nullptr, W, B, Kw, 0, 1.0f);
  else             gemm_body(A, nullptr, W, B, Qw, 0, CEXP);
}

__global__ __launch_bounds__(256) void out_kernel(
    const bf16* __restrict__ Sb, const bf16* __restrict__ Wob,
    const float* __restrict__ bo, float* __restrict__ out)
{
  gemm_body(nullptr, Sb, Wob, bo, out, 1, 1.0f);
}

// ---------------------------------------------------------------------------
// Flash attention, no-max softmax, 32x32x16 MFMA (2x FLOP per LDS fragment).
// Block = 128 q x 64-key tiles, 4 waves. Wave owns (32-key half) x (64 q =
// 2 q-tiles): every K/V/P fragment read feeds 2 MFMAs -> 2133 FLOP/LDS-cyc
// (2.4x the 16x16 version; LDS pipe was the measured bottleneck at 78us).
// K/V rows are 128B with T2 XOR swizzle (byte ^= (row&7)<<4); per-wave P
// [64q][32keys] rows 64B with (q&3)<<4 swizzle. Partial O / rowsum across
// the two key-half waves reduced once at the end through a separate LDS area.
// 32x32 C/D layout: col=lane&31, row=(reg&3)+8*(reg>>2)+4*(lane>>5).
// ---------------------------------------------------------------------------
__global__ __launch_bounds__(256, 2) void attn_kernel(
    const bf16* __restrict__ Qw, const bf16* __restrict__ Kw,
    const bf16* __restrict__ Vtg, float* __restrict__ scores,
    bf16* __restrict__ Sb)
{
  __shared__ __align__(16) char smem[32768];       // Ks 8K | Vt 8K | P 4x4K
  __shared__ __align__(16) float Ored[2][64][64];  // cross-wave O reduction
  __shared__ float RSred[2][64][2];

  const int tid  = threadIdx.x;
  const int wave = tid >> 6;
  const int lane = tid & 63;
  const int c    = lane & 31;
  const int hi   = lane >> 5;

  // bijective XCD swizzle over 512 blocks: XCD g%8 owns heads [4k,4k+4)
  const int g = blockIdx.x + (blockIdx.y << 4);
  const int slot = g >> 3;
  const int bh = ((g & 7) << 2) + (slot >> 4);
  const int q0 = (slot & 15) << 7;
  const size_t base = (size_t)bh << 17;            // bh * 2048 * 64

  const int qh = (wave & 1) * 64;                  // q-half of this wave
  const int kh = (wave >> 1) * 32;                 // key-half of this wave

  const int srow = tid >> 3;                       // staging: 32 rows/pass
  const int scb  = (tid & 7) * 16;                 // staging byte col

  char* Pw = smem + 16384 + wave * 4096;

  // loop-invariant Q B-frags: qf[qt][m] -> Q[q0+qh+qt*32+c][m*16+hi*8 ..+8]
  bf16x8 qf[2][4];
#pragma unroll
  for (int qt = 0; qt < 2; ++qt)
#pragma unroll
    for (int m = 0; m < 4; ++m)
      qf[qt][m] = *(const bf16x8*)
          &Qw[base + (size_t)(q0 + qh + qt * 32 + c) * 64 + m * 16 + hi * 8];

  floatx16 o[2][2] = {};     // [dk-half][q-tile]
  float rs[2] = {0.f, 0.f};

  bf16x8 kpf[2], vpf[2];
  auto load_kv = [&](int kt) {
#pragma unroll
    for (int rr = 0; rr < 2; ++rr) {
      const int row = rr * 32 + srow;
      kpf[rr] = *(const bf16x8*)&Kw[base + (size_t)(kt + row) * 64 + (tid & 7) * 8];
      vpf[rr] = *(const bf16x8*)&Vtg[base + (size_t)row * 2048 + kt + (tid & 7) * 8];
    }
  };
  load_kv(0);

  for (int kt = 0; kt < 2048; kt += 64) {
    __syncthreads();
#pragma unroll
    for (int rr = 0; rr < 2; ++rr) {
      const int row = rr * 32 + srow;
      const int swz = (row & 7) << 4;
      *(bf16x8*)(smem +        row * 128 + (scb ^ swz)) = kpf[rr];   // Ks
      *(bf16x8*)(smem + 8192 + row * 128 + (scb ^ swz)) = vpf[rr];   // Vt
    }
    __syncthreads();
    if (kt + 64 < 2048) load_kv(kt + 64);

    // S^T = K Q^T : A = K rows (this wave's 32 keys), B = Q frags (in reg)
    floatx16 s[2] = {};
    {
      const int row = kh + c;
      const int swz = (row & 7) << 4;
      __builtin_amdgcn_s_setprio(1);
#pragma unroll
      for (int m = 0; m < 4; ++m) {
        const bf16x8 a = *(const bf16x8*)(smem + row * 128 + ((m * 32 + hi * 16) ^ swz));
        s[0] = __builtin_amdgcn_mfma_f32_32x32x16_bf16(a, qf[0][m], s[0], 0, 0, 0);
        s[1] = __builtin_amdgcn_mfma_f32_32x32x16_bf16(a, qf[1][m], s[1], 0, 0, 0);
      }
      __builtin_amdgcn_s_setprio(0);
    }

    // exp2 + pack P^T to per-wave LDS [q][key_local], rows 64B swizzled
#pragma unroll
    for (int qt = 0; qt < 2; ++qt) {
      char* pr = Pw + (qt * 32 + c) * 64;
      const int psw = (c & 3) << 4;
#pragma unroll
      for (int gg = 0; gg < 4; ++gg) {
        bf16x4 pk;
#pragma unroll
        for (int i = 0; i < 4; ++i) {
          const float p = exp2f(s[qt][gg * 4 + i]);
          rs[qt] += p;
          pk[i] = (bf16)p;
        }
        *(bf16x4*)(pr + ((gg * 16 + hi * 8) ^ psw)) = pk;
      }
    }

    // O^T += V^T P^T : A = Vt rows (dk), B = P frags; each A/B read feeds 2 MFMAs
    __builtin_amdgcn_s_setprio(1);
#pragma unroll
    for (int t = 0; t < 2; ++t) {
      bf16x8 pb[2];
#pragma unroll
      for (int qt = 0; qt < 2; ++qt)
        pb[qt] = *(const bf16x8*)(Pw + (qt * 32 + c) * 64 + ((t * 32 + hi * 16) ^ ((c & 3) << 4)));
#pragma unroll
      for (int d = 0; d < 2; ++d) {
        const int row = d * 32 + c;
        const bf16x8 va = *(const bf16x8*)
            (smem + 8192 + row * 128 + ((kh * 2 + t * 32 + hi * 16) ^ ((row & 7) << 4)));
        o[d][0] = __builtin_amdgcn_mfma_f32_32x32x16_bf16(va, pb[0], o[d][0], 0, 0, 0);
        o[d][1] = __builtin_amdgcn_mfma_f32_32x32x16_bf16(va, pb[1], o[d][1], 0, 0, 0);
      }
    }
    __builtin_amdgcn_s_setprio(0);
  }

  // fold hi/lo lane halves (lanes l, l^32 share q, disjoint key subsets)
  rs[0] += __shfl_xor(rs[0], 32, 64);
  rs[1] += __shfl_xor(rs[1], 32, 64);

  // cross-wave reduction: waves 2,3 (kh=32) hand partials to waves 0,1
  if (wave >= 2) {
#pragma unroll
    for (int d = 0; d < 2; ++d)
#pragma unroll
      for (int qt = 0; qt < 2; ++qt)
#pragma unroll
        for (int gg = 0; gg < 4; ++gg) {
          floatx4 w4;
#pragma unroll
          for (int i = 0; i < 4; ++i) w4[i] = o[d][qt][gg * 4 + i];
          *(floatx4*)&Ored[wave - 2][lane][(d * 2 + qt) * 16 + gg * 4] = w4;
        }
    RSred[wave - 2][lane][0] = rs[0];
    RSred[wave - 2][lane][1] = rs[1];
  }
  __syncthreads();
  if (wave >= 2) return;

#pragma unroll
  for (int d = 0; d < 2; ++d)
#pragma unroll
    for (int qt = 0; qt < 2; ++qt)
#pragma unroll
      for (int gg = 0; gg < 4; ++gg) {
        const floatx4 r4 = *(const floatx4*)&Ored[wave][lane][(d * 2 + qt) * 16 + gg * 4];
#pragma unroll
        for (int i = 0; i < 4; ++i) o[d][qt][gg * 4 + i] += r4[i];
      }
  rs[0] += RSred[wave][lane][0];
  rs[1] += RSred[wave][lane][1];

  const float inv0 = 1.0f / rs[0];
  const float inv1 = 1.0f / rs[1];

#pragma unroll
  for (int qt = 0; qt < 2; ++qt) {
    const float inv = qt ? inv1 : inv0;
    const int q = q0 + qh + qt * 32 + c;
    float* sr = scores + base + (size_t)q * 64;
    bf16*  br = Sb + base + (size_t)q * 64;
#pragma unroll
    for (int d = 0; d < 2; ++d)
#pragma unroll
      for (int gg = 0; gg < 4; ++gg) {
        const int dk = d * 32 + gg * 8 + hi * 4;
        floatx4 v4;
        bf16x4 b4;
#pragma unroll
        for (int i = 0; i < 4; ++i) {
          const float v = o[d][qt][gg * 4 + i] * inv;
          v4[i] = v;
          b4[i] = (bf16)v;
        }
        *(floatx4*)(sr + dk) = v4;
        *(bf16x4*)(br + dk) = b4;
      }
  }
}

// ---------------------------------------------------------------------------
extern "C" void kernel_launch(void* const* d_in, const int* in_sizes, int n_in,
                              void* d_out, int out_size, void* d_ws, size_t ws_size,
                              hipStream_t stream) {
  const float* query = (const float*)d_in[0];
  const float* key   = (const float*)d_in[1];
  const float* value = (const float*)d_in[2];
  const float* Wq = (const float*)d_in[3];
  const float* bq = (const float*)d_in[4];
  const float* Wk = (const float*)d_in[5];
  const float* bk = (const float*)d_in[6];
  const float* Wv = (const float*)d_in[7];
  const float* bv = (const float*)d_in[8];
  const float* Wo = (const float*)d_in[9];
  const float* bo = (const float*)d_in[10];

  float* out    = (float*)d_out;
  float* scores = out + (size_t)4194304;   // second output (fp32)

  bf16* Wb  = (bf16*)d_ws;                 // 8 MB (Wq,Wk,Wv,Wo bf16)
  bf16* Qws = Wb + (size_t)4194304;        // [b,h,s,dk], pre-scaled by CEXP
  bf16* Kws = Qws + (size_t)4194304;       // [b,h,s,dk]
  bf16* Vws = Kws + (size_t)4194304;       // [b,h,dk,s] (transposed)
  bf16* Sb  = Vws + (size_t)4194304;       // bf16 copy of scores

  wcvt_kernel<<<dim3(1024, 4), 256, 0, stream>>>(Wq, Wk, Wv, Wo, Wb);
  qkv_kernel<<<dim3(32, 8, 3), 256, 0, stream>>>(query, key, value, Wb,
                                                 bq, bk, bv, Qws, Kws, Vws);
  attn_kernel<<<dim3(16, 32), 256, 0, stream>>>(Qws, Kws, Vws, scores, Sb);
  out_kernel<<<dim3(32, 8), 256, 0, stream>>>(Sb, Wb + (size_t)3145728, bo, out);
}

// Round 3
// 237.486 us; speedup vs baseline: 1.0327x; 1.0327x over previous
//
#include <hip/hip_runtime.h>
#include <stdint.h>
#include <math.h>

typedef __bf16 bf16;
typedef __bf16 bf16x4 __attribute__((ext_vector_type(4)));
typedef __bf16 bf16x8 __attribute__((ext_vector_type(8)));
typedef float floatx4 __attribute__((ext_vector_type(4)));
typedef float floatx16 __attribute__((ext_vector_type(16)));

#define CEXP 0.1803368801111204f  /* (1/8) * log2(e) */

// ---------------------------------------------------------------------------
// Weight pre-convert: fp32 [1024][1024] -> bf16, 4 matrices (Wq,Wk,Wv,Wo)
// ---------------------------------------------------------------------------
__global__ __launch_bounds__(256) void wcvt_kernel(
    const float* __restrict__ Wq, const float* __restrict__ Wk,
    const float* __restrict__ Wv, const float* __restrict__ Wo,
    bf16* __restrict__ dst)
{
  const float* src = (blockIdx.y == 0) ? Wq : (blockIdx.y == 1) ? Wk
                   : (blockIdx.y == 2) ? Wv : Wo;
  bf16* d = dst + (size_t)blockIdx.y * 1048576;
  const int i = (blockIdx.x * 256 + threadIdx.x) * 4;
  const floatx4 v = *(const floatx4*)(src + i);
  bf16x4 o;
#pragma unroll
  for (int j = 0; j < 4; ++j) o[j] = (bf16)v[j];
  *(bf16x4*)(d + i) = o;
}

// ---------------------------------------------------------------------------
// GEMM: C[4096,1024] = A @ Wb(bf16)^T + bias(fp32)
// 128x128 tile, BK=64, 4 waves, register-prefetch pipeline, LDS stride 72.
// mode 0: A fp32 direct; C bf16 [b,h,s,dk]
// mode 2: A fp32 direct; C bf16 [b,h,dk,s] (transposed V), LDS-coalesced store
// mode 1: A bf16 gathered from Sb [b,h,s,dk]; C fp32 [token][col]
// ---------------------------------------------------------------------------
__device__ __forceinline__ void gemm_body(
    const float* __restrict__ A, const bf16* __restrict__ Ab,
    const bf16* __restrict__ Wb, const float* __restrict__ bias,
    void* __restrict__ Cout, const int mode, const float oscale)
{
  __shared__ __align__(16) bf16 As[128 * 72];
  __shared__ __align__(16) bf16 Bs[128 * 72];
  const int tid  = threadIdx.x;
  const int wave = tid >> 6;
  const int lane = tid & 63;
  const int mlane = lane & 15;
  const int quad  = lane >> 4;
  const int m0 = blockIdx.x * 128;   // m-major grid
  const int n0 = blockIdx.y * 128;
  const int wm = (wave >> 1) * 64;
  const int wn = (wave & 1) * 64;
  const int arow = tid >> 4, ac4 = (tid & 15) * 4;  // fp32 A: 16 rows/pass
  const int wrow = tid >> 3, wc8 = (tid & 7) * 8;   // bf16: 32 rows/pass

  floatx4 a_pf[8];
  bf16x8  ab_pf[4];
  bf16x8  w_pf[4];

  auto load_a = [&](int k0) {
    if (mode == 1) {
#pragma unroll
      for (int c = 0; c < 4; ++c) {
        const int token = m0 + c * 32 + wrow;
        const int b = token >> 11, s = token & 2047;
        const int h = k0 >> 6;  // BK=64 stays within one head
        ab_pf[c] = *(const bf16x8*)(Ab + (((size_t)(b * 16 + h) * 2048 + s) << 6) + wc8);
      }
    } else {
#pragma unroll
      for (int rr = 0; rr < 8; ++rr)
        a_pf[rr] = *(const floatx4*)(A + (size_t)(m0 + rr * 16 + arow) * 1024 + k0 + ac4);
    }
  };
  auto load_w = [&](int k0) {
#pragma unroll
    for (int c = 0; c < 4; ++c)
      w_pf[c] = *(const bf16x8*)(Wb + (size_t)(n0 + c * 32 + wrow) * 1024 + k0 + wc8);
  };

  load_a(0);
  load_w(0);

  floatx4 acc[4][4] = {};

  for (int k0 = 0; k0 < 1024; k0 += 64) {
    if (mode == 1) {
#pragma unroll
      for (int c = 0; c < 4; ++c)
        *(bf16x8*)&As[(c * 32 + wrow) * 72 + wc8] = ab_pf[c];
    } else {
#pragma unroll
      for (int rr = 0; rr < 8; ++rr) {
        bf16x4 ac;
#pragma unroll
        for (int j = 0; j < 4; ++j) ac[j] = (bf16)a_pf[rr][j];
        *(bf16x4*)&As[(rr * 16 + arow) * 72 + ac4] = ac;
      }
    }
#pragma unroll
    for (int c = 0; c < 4; ++c)
      *(bf16x8*)&Bs[(c * 32 + wrow) * 72 + wc8] = w_pf[c];
    __syncthreads();

    if (k0 + 64 < 1024) { load_a(k0 + 64); load_w(k0 + 64); }

#pragma unroll
    for (int kk = 0; kk < 64; kk += 32) {
      bf16x8 af[4], bfr[4];
#pragma unroll
      for (int t = 0; t < 4; ++t) {
        af[t]  = *(const bf16x8*)&As[(wm + t * 16 + mlane) * 72 + kk + quad * 8];
        bfr[t] = *(const bf16x8*)&Bs[(wn + t * 16 + mlane) * 72 + kk + quad * 8];
      }
#pragma unroll
      for (int mt = 0; mt < 4; ++mt)
#pragma unroll
        for (int nt = 0; nt < 4; ++nt)
          acc[mt][nt] = __builtin_amdgcn_mfma_f32_16x16x32_bf16(
              af[mt], bfr[nt], acc[mt][nt], 0, 0, 0);
    }
    __syncthreads();
  }

  // epilogue
  if (mode == 2) {
    // Transpose the wave's 64x64 tile through LDS, then 16B-coalesced stores.
    bf16* T = (wave < 2) ? &As[wave * 4608] : &Bs[(wave - 2) * 4608];
#pragma unroll
    for (int nt = 0; nt < 4; ++nt) {
      const float bv = bias[n0 + wn + nt * 16 + mlane];
#pragma unroll
      for (int mt = 0; mt < 4; ++mt) {
        bf16x4 t4;
#pragma unroll
        for (int r = 0; r < 4; ++r)
          t4[r] = (bf16)((acc[mt][nt][r] + bv) * oscale);
        *(bf16x4*)&T[(nt * 16 + mlane) * 72 + mt * 16 + quad * 4] = t4;
      }
    }
    asm volatile("s_waitcnt lgkmcnt(0)" ::: "memory");  // wave-local transpose
    const int token0 = m0 + wm;            // 64-aligned -> single b
    const int bb = token0 >> 11;
    const int srow0 = token0 & 2047;
    const int h = (n0 + wn) >> 6;          // 64-aligned -> single h
    const int dl = lane >> 3;
    const int s8 = (lane & 7) * 8;
    bf16* outp = (bf16*)Cout + ((size_t)(bb * 16 + h) << 17);
#pragma unroll
    for (int p = 0; p < 8; ++p) {
      const int dk = p * 8 + dl;
      const bf16x8 v8 = *(const bf16x8*)&T[dk * 72 + s8];
      *(bf16x8*)&outp[((size_t)dk << 11) + srow0 + s8] = v8;
    }
    return;
  }

#pragma unroll
  for (int nt = 0; nt < 4; ++nt) {
    const int col = n0 + wn + nt * 16 + mlane;
    const float bv = bias[col];
#pragma unroll
    for (int mt = 0; mt < 4; ++mt) {
#pragma unroll
      for (int r = 0; r < 4; ++r) {
        const int row = m0 + wm + mt * 16 + quad * 4 + r;
        const float v = (acc[mt][nt][r] + bv) * oscale;
        if (mode == 0) {
          const int b = row >> 11, s = row & 2047;
          const int h = col >> 6, dk = col & 63;
          ((bf16*)Cout)[(((size_t)(b * 16 + h) * 2048 + s) << 6) + dk] = (bf16)v;
        } else {
          ((float*)Cout)[(size_t)row * 1024 + col] = v;
        }
      }
    }
  }
}

__global__ __launch_bounds__(256) void qkv_kernel(
    const float* __restrict__ q, const float* __restrict__ k, const float* __restrict__ v,
    const bf16* __restrict__ Wb,
    const float* __restrict__ bq, const float* __restrict__ bk, const float* __restrict__ bv,
    bf16* __restrict__ Qw, bf16* __restrict__ Kw, bf16* __restrict__ Vw)
{
  const int z = blockIdx.z;
  const float* A = (z == 0) ? q : (z == 1) ? k : v;
  const bf16* W  = Wb + (size_t)z * 1048576;
  const float* B = (z == 0) ? bq : (z == 1) ? bk : bv;
  if (z == 2)      gemm_body(A, nullptr, W, B, Vw, 2, 1.0f);
  else if (z == 1) gemm_body(A, nullptr, W, B, Kw, 0, 1.0f);
  else             gemm_body(A, nullptr, W, B, Qw, 0, CEXP);
}

__global__ __launch_bounds__(256) void out_kernel(
    const bf16* __restrict__ Sb, const bf16* __restrict__ Wob,
    const float* __restrict__ bo, float* __restrict__ out)
{
  gemm_body(nullptr, Sb, Wob, bo, out, 1, 1.0f);
}

// ---------------------------------------------------------------------------
// Flash attention, no-max softmax, 32x32x16 MFMA, P fully in-register (T12).
// Block = 128 q (4 waves x 32 q), 64-key tiles, wave covers ALL keys of the
// staged tile (2 key-subtiles ks). K/V staged in LDS with ROW STRIDE 136B
// (34 dwords; 34*16 == 0 mod 32) and b64-only access -> zero bank conflicts
// (measured 13.4M conflict-cyc = 27% of prior kernel). P handoff QK->PV via
// v_cvt_pk_bf16_f32 + v_permlane32_swap_b32: no P LDS roundtrip, no
// mid-iteration lgkmcnt(0) walls, no cross-wave reduction scratch.
// Layouts (harness-validated in round 2): A-frag row=lane&31, k=(lane>>5)*8+j;
// B-frag col=lane&31, same k; C col=lane&31(=q), row=(i&3)+8*(i>>2)+4*(lane>>5).
// ---------------------------------------------------------------------------
__global__ __launch_bounds__(256, 2) void attn_kernel(
    const bf16* __restrict__ Qw, const bf16* __restrict__ Kw,
    const bf16* __restrict__ Vtg, float* __restrict__ scores,
    bf16* __restrict__ Sb)
{
  __shared__ __align__(16) char smem[2 * 64 * 136];  // Ks | Vt, 136B rows
  char* KsB = smem;
  char* VsB = smem + 64 * 136;

  const int tid  = threadIdx.x;
  const int wave = tid >> 6;
  const int lane = tid & 63;
  const int c    = lane & 31;
  const int hi   = lane >> 5;

  // bijective XCD swizzle over 512 blocks: XCD g%8 owns heads [4k,4k+4)
  const int g = blockIdx.x + (blockIdx.y << 4);
  const int slot = g >> 3;
  const int bh = ((g & 7) << 2) + (slot >> 4);
  const int q0 = (slot & 15) << 7;
  const size_t base = (size_t)bh << 17;            // bh * 2048 * 64

  const int srow = tid >> 2;                       // staging: 64 rows, 4 thr/row
  const int sce  = (tid & 3) * 16;                 // element col (32B/thread)

  // loop-invariant Q B-frags: qf[m] -> Q[q0+wave*32+c][m*16+hi*8 ..+8]
  bf16x8 qf[4];
#pragma unroll
  for (int m = 0; m < 4; ++m)
    qf[m] = *(const bf16x8*)
        &Qw[base + (size_t)(q0 + wave * 32 + c) * 64 + m * 16 + hi * 8];

  floatx16 o[2] = {};          // [dk-half]; col=q=c, row=dk
  float rs = 0.f;

  bf16x8 kpf[2], vpf[2];
  auto load_kv = [&](int kt) {
    const bf16* kp = &Kw[base + (size_t)(kt + srow) * 64 + sce];
    kpf[0] = *(const bf16x8*)kp;
    kpf[1] = *(const bf16x8*)(kp + 8);
    const bf16* vp = &Vtg[base + (size_t)srow * 2048 + kt + sce];
    vpf[0] = *(const bf16x8*)vp;
    vpf[1] = *(const bf16x8*)(vp + 8);
  };
  load_kv(0);

  for (int kt = 0; kt < 2048; kt += 64) {
    __syncthreads();
    {
      char* kr = KsB + srow * 136 + (tid & 3) * 32;
      char* vr = VsB + srow * 136 + (tid & 3) * 32;
      *(bf16x4*)(kr +  0) = ((const bf16x4*)&kpf[0])[0];
      *(bf16x4*)(kr +  8) = ((const bf16x4*)&kpf[0])[1];
      *(bf16x4*)(kr + 16) = ((const bf16x4*)&kpf[1])[0];
      *(bf16x4*)(kr + 24) = ((const bf16x4*)&kpf[1])[1];
      *(bf16x4*)(vr +  0) = ((const bf16x4*)&vpf[0])[0];
      *(bf16x4*)(vr +  8) = ((const bf16x4*)&vpf[0])[1];
      *(bf16x4*)(vr + 16) = ((const bf16x4*)&vpf[1])[0];
      *(bf16x4*)(vr + 24) = ((const bf16x4*)&vpf[1])[1];
    }
    __syncthreads();
    if (kt + 64 < 2048) load_kv(kt + 64);

#pragma unroll
    for (int ks = 0; ks < 2; ++ks) {
      // S^T = K Q^T : A = K rows (keys ks*32+c), B = Q frags (reg)
      const char* krow = KsB + (ks * 32 + c) * 136;
      floatx16 s = {};
      __builtin_amdgcn_s_setprio(1);
#pragma unroll
      for (int m = 0; m < 4; ++m) {
        bf16x8 a;
        ((bf16x4*)&a)[0] = *(const bf16x4*)(krow + m * 32 + hi * 16);
        ((bf16x4*)&a)[1] = *(const bf16x4*)(krow + m * 32 + hi * 16 + 8);
        s = __builtin_amdgcn_mfma_f32_32x32x16_bf16(a, qf[m], s, 0, 0, 0);
      }
      __builtin_amdgcn_s_setprio(0);

      // exp2 + rowsum; s reg i holds key_local = 8*(i>>2) + (i&3) + 4*hi
      float p[16];
#pragma unroll
      for (int i = 0; i < 16; ++i) p[i] = exp2f(s[i]);
#pragma unroll
      for (int i = 0; i < 16; ++i) rs += p[i];

      // pack: ulo[g] = keys 8g+4hi+{0,1}, uhi[g] = keys 8g+4hi+{2,3}
      uint32_t ulo[4], uhi[4];
#pragma unroll
      for (int gg = 0; gg < 4; ++gg) {
        asm("v_cvt_pk_bf16_f32 %0, %1, %2"
            : "=v"(ulo[gg]) : "v"(p[4 * gg]), "v"(p[4 * gg + 1]));
        asm("v_cvt_pk_bf16_f32 %0, %1, %2"
            : "=v"(uhi[gg]) : "v"(p[4 * gg + 2]), "v"(p[4 * gg + 3]));
      }

      // O^T += V^T P^T : B-frag(t) needs keys 16t+8hi+{0..7}; assemble via
      // permlane32_swap: {w0,w2} = swap(ulo[2t], ulo[2t+1]),
      //                  {w1,w3} = swap(uhi[2t], uhi[2t+1]).
      __builtin_amdgcn_s_setprio(1);
#pragma unroll
      for (int t = 0; t < 2; ++t) {
        uint32_t w0 = ulo[2 * t], w2 = ulo[2 * t + 1];
        uint32_t w1 = uhi[2 * t], w3 = uhi[2 * t + 1];
        asm("v_permlane32_swap_b32 %0, %1" : "+v"(w0), "+v"(w2));
        asm("v_permlane32_swap_b32 %0, %1" : "+v"(w1), "+v"(w3));
        union { bf16x8 v; uint32_t w[4]; } pu;
        pu.w[0] = w0; pu.w[1] = w1; pu.w[2] = w2; pu.w[3] = w3;
#pragma unroll
        for (int d = 0; d < 2; ++d) {
          const char* vrow = VsB + (d * 32 + c) * 136 + ks * 64 + t * 32 + hi * 16;
          bf16x8 va;
          ((bf16x4*)&va)[0] = *(const bf16x4*)(vrow);
          ((bf16x4*)&va)[1] = *(const bf16x4*)(vrow + 8);
          o[d] = __builtin_amdgcn_mfma_f32_32x32x16_bf16(va, pu.v, o[d], 0, 0, 0);
        }
      }
      __builtin_amdgcn_s_setprio(0);
    }
  }

  // lanes (c,0)/(c,1) share q=c, hold complementary key subsets
  rs += __shfl_xor(rs, 32, 64);
  const float inv = 1.0f / rs;

  const int q = q0 + wave * 32 + c;
  float* sr = scores + base + (size_t)q * 64;
  bf16*  br = Sb + base + (size_t)q * 64;
#pragma unroll
  for (int d = 0; d < 2; ++d)
#pragma unroll
    for (int gg = 0; gg < 4; ++gg) {
      const int dk = d * 32 + gg * 8 + hi * 4;
      floatx4 v4;
      bf16x4 b4;
#pragma unroll
      for (int i = 0; i < 4; ++i) {
        const float v = o[d][gg * 4 + i] * inv;
        v4[i] = v;
        b4[i] = (bf16)v;
      }
      *(floatx4*)(sr + dk) = v4;
      *(bf16x4*)(br + dk) = b4;
    }
}

// ---------------------------------------------------------------------------
extern "C" void kernel_launch(void* const* d_in, const int* in_sizes, int n_in,
                              void* d_out, int out_size, void* d_ws, size_t ws_size,
                              hipStream_t stream) {
  const float* query = (const float*)d_in[0];
  const float* key   = (const float*)d_in[1];
  const float* value = (const float*)d_in[2];
  const float* Wq = (const float*)d_in[3];
  const float* bq = (const float*)d_in[4];
  const float* Wk = (const float*)d_in[5];
  const float* bk = (const float*)d_in[6];
  const float* Wv = (const float*)d_in[7];
  const float* bv = (const float*)d_in[8];
  const float* Wo = (const float*)d_in[9];
  const float* bo = (const float*)d_in[10];

  float* out    = (float*)d_out;
  float* scores = out + (size_t)4194304;   // second output (fp32)

  bf16* Wb  = (bf16*)d_ws;                 // 8 MB (Wq,Wk,Wv,Wo bf16)
  bf16* Qws = Wb + (size_t)4194304;        // [b,h,s,dk], pre-scaled by CEXP
  bf16* Kws = Qws + (size_t)4194304;       // [b,h,s,dk]
  bf16* Vws = Kws + (size_t)4194304;       // [b,h,dk,s] (transposed)
  bf16* Sb  = Vws + (size_t)4194304;       // bf16 copy of scores

  wcvt_kernel<<<dim3(1024, 4), 256, 0, stream>>>(Wq, Wk, Wv, Wo, Wb);
  qkv_kernel<<<dim3(32, 8, 3), 256, 0, stream>>>(query, key, value, Wb,
                                                 bq, bk, bv, Qws, Kws, Vws);
  attn_kernel<<<dim3(16, 32), 256, 0, stream>>>(Qws, Kws, Vws, scores, Sb);
  out_kernel<<<dim3(32, 8), 256, 0, stream>>>(Sb, Wb + (size_t)3145728, bo, out);
}

// Round 5
// 228.385 us; speedup vs baseline: 1.0738x; 1.0399x over previous
//
#include <hip/hip_runtime.h>
#include <stdint.h>
#include <math.h>

typedef __bf16 bf16;
typedef __bf16 bf16x4 __attribute__((ext_vector_type(4)));
typedef __bf16 bf16x8 __attribute__((ext_vector_type(8)));
typedef float floatx4 __attribute__((ext_vector_type(4)));
typedef float floatx16 __attribute__((ext_vector_type(16)));

#define CEXP 0.1803368801111204f  /* (1/8) * log2(e) */

// ---------------------------------------------------------------------------
// Weight pre-convert: fp32 [1024][1024] -> bf16, 4 matrices (Wq,Wk,Wv,Wo)
// ---------------------------------------------------------------------------
__global__ __launch_bounds__(256) void wcvt_kernel(
    const float* __restrict__ Wq, const float* __restrict__ Wk,
    const float* __restrict__ Wv, const float* __restrict__ Wo,
    bf16* __restrict__ dst)
{
  const float* src = (blockIdx.y == 0) ? Wq : (blockIdx.y == 1) ? Wk
                   : (blockIdx.y == 2) ? Wv : Wo;
  bf16* d = dst + (size_t)blockIdx.y * 1048576;
  const int i = (blockIdx.x * 256 + threadIdx.x) * 4;
  const floatx4 v = *(const floatx4*)(src + i);
  bf16x4 o;
#pragma unroll
  for (int j = 0; j < 4; ++j) o[j] = (bf16)v[j];
  *(bf16x4*)(d + i) = o;
}

// ---------------------------------------------------------------------------
// GEMM: C[4096,1024] = A @ Wb(bf16)^T + bias(fp32)
// 128x128 tile, BK=64, 4 waves, register-prefetch pipeline, LDS stride 72.
// mode 0: A fp32 direct; C bf16 [b,h,s,dk]
// mode 2: A fp32 direct; C bf16 [b,h,dk,s] (transposed V), LDS-coalesced store
// mode 1: A bf16 gathered from Sb [b,h,s,dk]; C fp32 [token][col]
// ---------------------------------------------------------------------------
__device__ __forceinline__ void gemm_body(
    const float* __restrict__ A, const bf16* __restrict__ Ab,
    const bf16* __restrict__ Wb, const float* __restrict__ bias,
    void* __restrict__ Cout, const int mode, const float oscale)
{
  __shared__ __align__(16) bf16 As[128 * 72];
  __shared__ __align__(16) bf16 Bs[128 * 72];
  const int tid  = threadIdx.x;
  const int wave = tid >> 6;
  const int lane = tid & 63;
  const int mlane = lane & 15;
  const int quad  = lane >> 4;
  const int m0 = blockIdx.x * 128;   // m-major grid
  const int n0 = blockIdx.y * 128;
  const int wm = (wave >> 1) * 64;
  const int wn = (wave & 1) * 64;
  const int arow = tid >> 4, ac4 = (tid & 15) * 4;  // fp32 A: 16 rows/pass
  const int wrow = tid >> 3, wc8 = (tid & 7) * 8;   // bf16: 32 rows/pass

  floatx4 a_pf[8];
  bf16x8  ab_pf[4];
  bf16x8  w_pf[4];

  auto load_a = [&](int k0) {
    if (mode == 1) {
#pragma unroll
      for (int c = 0; c < 4; ++c) {
        const int token = m0 + c * 32 + wrow;
        const int b = token >> 11, s = token & 2047;
        const int h = k0 >> 6;  // BK=64 stays within one head
        ab_pf[c] = *(const bf16x8*)(Ab + (((size_t)(b * 16 + h) * 2048 + s) << 6) + wc8);
      }
    } else {
#pragma unroll
      for (int rr = 0; rr < 8; ++rr)
        a_pf[rr] = *(const floatx4*)(A + (size_t)(m0 + rr * 16 + arow) * 1024 + k0 + ac4);
    }
  };
  auto load_w = [&](int k0) {
#pragma unroll
    for (int c = 0; c < 4; ++c)
      w_pf[c] = *(const bf16x8*)(Wb + (size_t)(n0 + c * 32 + wrow) * 1024 + k0 + wc8);
  };

  load_a(0);
  load_w(0);

  floatx4 acc[4][4] = {};

  for (int k0 = 0; k0 < 1024; k0 += 64) {
    if (mode == 1) {
#pragma unroll
      for (int c = 0; c < 4; ++c)
        *(bf16x8*)&As[(c * 32 + wrow) * 72 + wc8] = ab_pf[c];
    } else {
#pragma unroll
      for (int rr = 0; rr < 8; ++rr) {
        bf16x4 ac;
#pragma unroll
        for (int j = 0; j < 4; ++j) ac[j] = (bf16)a_pf[rr][j];
        *(bf16x4*)&As[(rr * 16 + arow) * 72 + ac4] = ac;
      }
    }
#pragma unroll
    for (int c = 0; c < 4; ++c)
      *(bf16x8*)&Bs[(c * 32 + wrow) * 72 + wc8] = w_pf[c];
    __syncthreads();

    if (k0 + 64 < 1024) { load_a(k0 + 64); load_w(k0 + 64); }

#pragma unroll
    for (int kk = 0; kk < 64; kk += 32) {
      bf16x8 af[4], bfr[4];
#pragma unroll
      for (int t = 0; t < 4; ++t) {
        af[t]  = *(const bf16x8*)&As[(wm + t * 16 + mlane) * 72 + kk + quad * 8];
        bfr[t] = *(const bf16x8*)&Bs[(wn + t * 16 + mlane) * 72 + kk + quad * 8];
      }
#pragma unroll
      for (int mt = 0; mt < 4; ++mt)
#pragma unroll
        for (int nt = 0; nt < 4; ++nt)
          acc[mt][nt] = __builtin_amdgcn_mfma_f32_16x16x32_bf16(
              af[mt], bfr[nt], acc[mt][nt], 0, 0, 0);
    }
    __syncthreads();
  }

  // epilogue
  if (mode == 2) {
    // Transpose the wave's 64x64 tile through LDS, then 16B-coalesced stores.
    bf16* T = (wave < 2) ? &As[wave * 4608] : &Bs[(wave - 2) * 4608];
#pragma unroll
    for (int nt = 0; nt < 4; ++nt) {
      const float bv = bias[n0 + wn + nt * 16 + mlane];
#pragma unroll
      for (int mt = 0; mt < 4; ++mt) {
        bf16x4 t4;
#pragma unroll
        for (int r = 0; r < 4; ++r)
          t4[r] = (bf16)((acc[mt][nt][r] + bv) * oscale);
        *(bf16x4*)&T[(nt * 16 + mlane) * 72 + mt * 16 + quad * 4] = t4;
      }
    }
    asm volatile("s_waitcnt lgkmcnt(0)" ::: "memory");  // wave-local transpose
    const int token0 = m0 + wm;            // 64-aligned -> single b
    const int bb = token0 >> 11;
    const int srow0 = token0 & 2047;
    const int h = (n0 + wn) >> 6;          // 64-aligned -> single h
    const int dl = lane >> 3;
    const int s8 = (lane & 7) * 8;
    bf16* outp = (bf16*)Cout + ((size_t)(bb * 16 + h) << 17);
#pragma unroll
    for (int p = 0; p < 8; ++p) {
      const int dk = p * 8 + dl;
      const bf16x8 v8 = *(const bf16x8*)&T[dk * 72 + s8];
      *(bf16x8*)&outp[((size_t)dk << 11) + srow0 + s8] = v8;
    }
    return;
  }

#pragma unroll
  for (int nt = 0; nt < 4; ++nt) {
    const int col = n0 + wn + nt * 16 + mlane;
    const float bv = bias[col];
#pragma unroll
    for (int mt = 0; mt < 4; ++mt) {
#pragma unroll
      for (int r = 0; r < 4; ++r) {
        const int row = m0 + wm + mt * 16 + quad * 4 + r;
        const float v = (acc[mt][nt][r] + bv) * oscale;
        if (mode == 0) {
          const int b = row >> 11, s = row & 2047;
          const int h = col >> 6, dk = col & 63;
          ((bf16*)Cout)[(((size_t)(b * 16 + h) * 2048 + s) << 6) + dk] = (bf16)v;
        } else {
          ((float*)Cout)[(size_t)row * 1024 + col] = v;
        }
      }
    }
  }
}

__global__ __launch_bounds__(256) void qkv_kernel(
    const float* __restrict__ q, const float* __restrict__ k, const float* __restrict__ v,
    const bf16* __restrict__ Wb,
    const float* __restrict__ bq, const float* __restrict__ bk, const float* __restrict__ bv,
    bf16* __restrict__ Qw, bf16* __restrict__ Kw, bf16* __restrict__ Vw)
{
  const int z = blockIdx.z;
  const float* A = (z == 0) ? q : (z == 1) ? k : v;
  const bf16* W  = Wb + (size_t)z * 1048576;
  const float* B = (z == 0) ? bq : (z == 1) ? bk : bv;
  if (z == 2)      gemm_body(A, nullptr, W, B, Vw, 2, 1.0f);
  else if (z == 1) gemm_body(A, nullptr, W, B, Kw, 0, 1.0f);
  else             gemm_body(A, nullptr, W, B, Qw, 0, CEXP);
}

__global__ __launch_bounds__(256) void out_kernel(
    const bf16* __restrict__ Sb, const bf16* __restrict__ Wob,
    const float* __restrict__ bo, float* __restrict__ out)
{
  gemm_body(nullptr, Sb, Wob, bo, out, 1, 1.0f);
}

// ---------------------------------------------------------------------------
// Flash attention, no-max softmax, 32x32x16 MFMA, P fully in-register.
// Round-5 = round-3 (69us, PASSED, 0 bank conflicts) + two safe deltas:
//  - double-buffered K/V LDS, ONE __syncthreads per 64-key tile (stage of
//    tile k+1 into the disjoint buffer overlaps compute of tile k)
//  - __builtin_amdgcn_exp2f: raw v_exp_f32 WITH compiler-visible hazard
//    handling (round-4's inline-asm exp + ones-MFMA rowsum failed: an MFMA
//    immediately consuming inline-asm permlane outputs is a VALU->MFMA
//    hazard the recognizer can't see through INLINE_ASM producers).
// Rowsum stays on the round-3-proven VALU path (+shfl_xor(32)).
// K/V rows keep the conflict-free 136B stride, b64-only access.
// ---------------------------------------------------------------------------
__global__ __launch_bounds__(256, 2) void attn_kernel(
    const bf16* __restrict__ Qw, const bf16* __restrict__ Kw,
    const bf16* __restrict__ Vtg, float* __restrict__ scores,
    bf16* __restrict__ Sb)
{
  // 2 buffers x (Ks 64x136B | Vt 64x136B) = 34816 B
  __shared__ __align__(16) char smem[2 * 2 * 64 * 136];

  const int tid  = threadIdx.x;
  const int wave = tid >> 6;
  const int lane = tid & 63;
  const int c    = lane & 31;
  const int hi   = lane >> 5;

  // bijective XCD swizzle over 512 blocks: XCD g%8 owns heads [4k,4k+4)
  const int g = blockIdx.x + (blockIdx.y << 4);
  const int slot = g >> 3;
  const int bh = ((g & 7) << 2) + (slot >> 4);
  const int q0 = (slot & 15) << 7;
  const size_t base = (size_t)bh << 17;            // bh * 2048 * 64

  const int srow = tid >> 2;                       // staging: 64 rows, 4 thr/row
  const int sce  = (tid & 3) * 16;                 // element col (32B/thread)

  // loop-invariant Q B-frags: qf[m] -> Q[q0+wave*32+c][m*16+hi*8 ..+8]
  bf16x8 qf[4];
#pragma unroll
  for (int m = 0; m < 4; ++m)
    qf[m] = *(const bf16x8*)
        &Qw[base + (size_t)(q0 + wave * 32 + c) * 64 + m * 16 + hi * 8];

  floatx16 o[2] = {};          // [dk-half]; col=q=c, row=dk
  float rs = 0.f;

  bf16x8 kpf[2], vpf[2];
  auto load_kv = [&](int kt) {
    const bf16* kp = &Kw[base + (size_t)(kt + srow) * 64 + sce];
    kpf[0] = *(const bf16x8*)kp;
    kpf[1] = *(const bf16x8*)(kp + 8);
    const bf16* vp = &Vtg[base + (size_t)srow * 2048 + kt + sce];
    vpf[0] = *(const bf16x8*)vp;
    vpf[1] = *(const bf16x8*)(vp + 8);
  };
  auto stage = [&](int b) {
    char* kr = smem + b * 17408 + srow * 136 + (tid & 3) * 32;
    char* vr = kr + 8704;
    *(bf16x4*)(kr +  0) = ((const bf16x4*)&kpf[0])[0];
    *(bf16x4*)(kr +  8) = ((const bf16x4*)&kpf[0])[1];
    *(bf16x4*)(kr + 16) = ((const bf16x4*)&kpf[1])[0];
    *(bf16x4*)(kr + 24) = ((const bf16x4*)&kpf[1])[1];
    *(bf16x4*)(vr +  0) = ((const bf16x4*)&vpf[0])[0];
    *(bf16x4*)(vr +  8) = ((const bf16x4*)&vpf[0])[1];
    *(bf16x4*)(vr + 16) = ((const bf16x4*)&vpf[1])[0];
    *(bf16x4*)(vr + 24) = ((const bf16x4*)&vpf[1])[1];
  };

  load_kv(0);
  stage(0);
  load_kv(64);
  __syncthreads();

  for (int kt = 0; kt < 2048; kt += 64) {
    const int cur = (kt >> 6) & 1;
    // stage next tile into the OTHER buffer (prev readers of that buffer
    // passed the last barrier); issue the following tile's global loads.
    if (kt + 64 < 2048) {
      stage(cur ^ 1);
      if (kt + 128 < 2048) load_kv(kt + 128);
    }
    const char* KsB = smem + cur * 17408;
    const char* VsB = KsB + 8704;

#pragma unroll
    for (int ks = 0; ks < 2; ++ks) {
      // S^T = K Q^T : A = K rows (keys ks*32+c), B = Q frags (reg)
      const char* krow = KsB + (ks * 32 + c) * 136;
      floatx16 s = {};
      __builtin_amdgcn_s_setprio(1);
#pragma unroll
      for (int m = 0; m < 4; ++m) {
        bf16x8 a;
        ((bf16x4*)&a)[0] = *(const bf16x4*)(krow + m * 32 + hi * 16);
        ((bf16x4*)&a)[1] = *(const bf16x4*)(krow + m * 32 + hi * 16 + 8);
        s = __builtin_amdgcn_mfma_f32_32x32x16_bf16(a, qf[m], s, 0, 0, 0);
      }
      __builtin_amdgcn_s_setprio(0);

      // raw-HW exp2 (compiler-visible builtin); reg i holds
      // key_local = 8*(i>>2) + (i&3) + 4*hi
      float p[16];
#pragma unroll
      for (int i = 0; i < 16; ++i) p[i] = __builtin_amdgcn_exp2f(s[i]);
#pragma unroll
      for (int i = 0; i < 16; ++i) rs += p[i];

      // pack: ulo[g] = keys 8g+4hi+{0,1}, uhi[g] = keys 8g+4hi+{2,3}
      uint32_t ulo[4], uhi[4];
#pragma unroll
      for (int gg = 0; gg < 4; ++gg) {
        asm("v_cvt_pk_bf16_f32 %0, %1, %2"
            : "=v"(ulo[gg]) : "v"(p[4 * gg]), "v"(p[4 * gg + 1]));
        asm("v_cvt_pk_bf16_f32 %0, %1, %2"
            : "=v"(uhi[gg]) : "v"(p[4 * gg + 2]), "v"(p[4 * gg + 3]));
      }

      // O^T += V^T P^T : B-frag(t) needs keys 16t+8hi+{0..7}; assemble via
      // permlane32_swap: {w0,w2} = swap(ulo[2t], ulo[2t+1]),
      //                  {w1,w3} = swap(uhi[2t], uhi[2t+1]).
      __builtin_amdgcn_s_setprio(1);
#pragma unroll
      for (int t = 0; t < 2; ++t) {
        uint32_t w0 = ulo[2 * t], w2 = ulo[2 * t + 1];
        uint32_t w1 = uhi[2 * t], w3 = uhi[2 * t + 1];
        asm("v_permlane32_swap_b32 %0, %1" : "+v"(w0), "+v"(w2));
        asm("v_permlane32_swap_b32 %0, %1" : "+v"(w1), "+v"(w3));
        union { bf16x8 v; uint32_t w[4]; } pu;
        pu.w[0] = w0; pu.w[1] = w1; pu.w[2] = w2; pu.w[3] = w3;
#pragma unroll
        for (int d = 0; d < 2; ++d) {
          const char* vrow = VsB + (d * 32 + c) * 136 + ks * 64 + t * 32 + hi * 16;
          bf16x8 va;
          ((bf16x4*)&va)[0] = *(const bf16x4*)(vrow);
          ((bf16x4*)&va)[1] = *(const bf16x4*)(vrow + 8);
          o[d] = __builtin_amdgcn_mfma_f32_32x32x16_bf16(va, pu.v, o[d], 0, 0, 0);
        }
      }
      __builtin_amdgcn_s_setprio(0);
    }
    __syncthreads();
  }

  // lanes (c,0)/(c,1) share q=c, hold complementary key subsets
  rs += __shfl_xor(rs, 32, 64);
  const float inv = 1.0f / rs;

  const int q = q0 + wave * 32 + c;
  float* sr = scores + base + (size_t)q * 64;
  bf16*  br = Sb + base + (size_t)q * 64;
#pragma unroll
  for (int d = 0; d < 2; ++d)
#pragma unroll
    for (int gg = 0; gg < 4; ++gg) {
      const int dk = d * 32 + gg * 8 + hi * 4;
      floatx4 v4;
      bf16x4 b4;
#pragma unroll
      for (int i = 0; i < 4; ++i) {
        const float v = o[d][gg * 4 + i] * inv;
        v4[i] = v;
        b4[i] = (bf16)v;
      }
      *(floatx4*)(sr + dk) = v4;
      *(bf16x4*)(br + dk) = b4;
    }
}

// ---------------------------------------------------------------------------
extern "C" void kernel_launch(void* const* d_in, const int* in_sizes, int n_in,
                              void* d_out, int out_size, void* d_ws, size_t ws_size,
                              hipStream_t stream) {
  const float* query = (const float*)d_in[0];
  const float* key   = (const float*)d_in[1];
  const float* value = (const float*)d_in[2];
  const float* Wq = (const float*)d_in[3];
  const float* bq = (const float*)d_in[4];
  const float* Wk = (const float*)d_in[5];
  const float* bk = (const float*)d_in[6];
  const float* Wv = (const float*)d_in[7];
  const float* bv = (const float*)d_in[8];
  const float* Wo = (const float*)d_in[9];
  const float* bo = (const float*)d_in[10];

  float* out    = (float*)d_out;
  float* scores = out + (size_t)4194304;   // second output (fp32)

  bf16* Wb  = (bf16*)d_ws;                 // 8 MB (Wq,Wk,Wv,Wo bf16)
  bf16* Qws = Wb + (size_t)4194304;        // [b,h,s,dk], pre-scaled by CEXP
  bf16* Kws = Qws + (size_t)4194304;       // [b,h,s,dk]
  bf16* Vws = Kws + (size_t)4194304;       // [b,h,dk,s] (transposed)
  bf16* Sb  = Vws + (size_t)4194304;       // bf16 copy of scores

  wcvt_kernel<<<dim3(1024, 4), 256, 0, stream>>>(Wq, Wk, Wv, Wo, Wb);
  qkv_kernel<<<dim3(32, 8, 3), 256, 0, stream>>>(query, key, value, Wb,
                                                 bq, bk, bv, Qws, Kws, Vws);
  attn_kernel<<<dim3(16, 32), 256, 0, stream>>>(Qws, Kws, Vws, scores, Sb);
  out_kernel<<<dim3(32, 8), 256, 0, stream>>>(Sb, Wb + (size_t)3145728, bo, out);
}